// Round 9
// baseline (208.342 us; speedup 1.0000x reference)
//
#include <hip/hip_runtime.h>

// Workspace layout (float offsets)
#define WS_M      0        // Mt[r*100+p] = M[p][r] where M = w_lin2 @ w_lin1, 10000 floats
#define WS_K      10000    // K[c][a][b][ci][u][v], 2646 floats
#define WS_BETA   12646    // beta[c][a][b], 18 floats
#define WS_W9     12664    // W9[c][ci][dy][dx], 486 floats
#define WS_BT     13150    // beta_tot[c] (interior combined bias), 2 floats
#define WS_INI    16384    // ini[b][c][h][w] f32, 1,638,400 floats
#define WS_UIT    (16384 + 1638400)      // uiL[bc][l][128] bf16 (halves at k=0,64)
#define WS_UFT    (16384 + 2*1638400)    // ufL[bc][l][128] bf16

typedef short bf16x8 __attribute__((ext_vector_type(8)));
typedef float f32x4  __attribute__((ext_vector_type(4)));

__device__ inline ushort f2bf(float f) {   // round-to-nearest-even
    unsigned u = __float_as_uint(f);
    unsigned r = (u + 0x7fffu + ((u >> 16) & 1u)) >> 16;
    return (ushort)r;
}

// ---------------------------------------------------------------------------
// Prep. blocks 0..39: Mt. blocks 40..42: K (block 40 also Beta+Bt).
// blocks 43..44: W9 from raw weights.
__global__ __launch_bounds__(256) void k_prep(const float* __restrict__ wl1,
                                              const float* __restrict__ wl2,
                                              const float* __restrict__ wc1,
                                              const float* __restrict__ bc1,
                                              const float* __restrict__ wc2,
                                              const float* __restrict__ bc2,
                                              float* __restrict__ ws) {
    int blk = blockIdx.x;
    int t = threadIdx.x;
    if (blk < 40) {
        int idx = blk * 256 + t;
        if (idx < 10000) {
            int p = idx / 100, r = idx % 100;
            float s = 0.f;
            for (int q = 0; q < 200; ++q)
                s += wl2[p * 200 + q] * wl1[q * 100 + r];
            ws[WS_M + r * 100 + p] = s;
        }
        return;
    }
    __shared__ float swc1[9408];   // 64*3*49
    __shared__ float swc2[1152];   // 2*64*9
    __shared__ float sBeta[18];
    for (int i = t; i < 9408; i += 256) swc1[i] = wc1[i];
    for (int i = t; i < 1152; i += 256) swc2[i] = wc2[i];
    __syncthreads();
    if (blk < 43) {
        int base = (blk - 40) * 882;
        for (int ii = t; ii < 882; ii += 256) {
            int idx = base + ii;
            int v = idx % 7; int t1 = idx / 7;
            int u = t1 % 7;  int t2 = t1 / 7;
            int ci = t2 % 3; int t3 = t2 / 3;
            int b = t3 % 3;  int t4 = t3 / 3;
            int a = t4 % 3;  int c = t4 / 3;
            float s = 0.f;
            for (int c64 = 0; c64 < 64; ++c64)
                s += swc2[((c * 64 + c64) * 3 + a) * 3 + b] *
                     swc1[((c64 * 3 + ci) * 7 + u) * 7 + v];
            ws[WS_K + idx] = s;
        }
        if (blk == 40) {
            if (t < 18) {
                int b = t % 3; int a = (t / 3) % 3; int c = t / 9;
                float s = 0.f;
                for (int c64 = 0; c64 < 64; ++c64)
                    s += swc2[((c * 64 + c64) * 3 + a) * 3 + b] * bc1[c64];
                sBeta[t] = s; ws[WS_BETA + t] = s;
            }
            __syncthreads();
            if (t < 2) {
                float s = bc2[t];
                for (int j2 = 0; j2 < 9; ++j2) s += sBeta[t * 9 + j2];
                ws[WS_BT + t] = s;
            }
        }
    } else {
        int idx = (blk - 43) * 243 + t;
        if (t < 243) {
            int dx = idx % 9; int t1 = idx / 9;
            int dy = t1 % 9;  int t2 = t1 / 9;
            int ci = t2 % 3;  int c = t2 / 3;
            float s = 0.f;
            for (int a = 0; a < 3; ++a) {
                int u = dy - a; if (u < 0 || u > 6) continue;
                for (int b = 0; b < 3; ++b) {
                    int v = dx - b; if (v < 0 || v > 6) continue;
                    for (int c64 = 0; c64 < 64; ++c64)
                        s += swc2[((c * 64 + c64) * 3 + a) * 3 + b] *
                             swc1[((c64 * 3 + ci) * 7 + u) * 7 + v];
                }
            }
            ws[WS_W9 + idx] = s;   // layout c*243 + ci*81 + dy*9 + dx
        }
    }
}

// ---------------------------------------------------------------------------
// Conv with inline exact ring-correction. 20x20 tile, grid (16,16,8) = 2048
// blocks, LDS 12.1 KB -> 8/CU. Writes ini as coalesced float2 (both channels,
// all pixels — edge blocks produce exact ring values inline, no second pass).
__global__ __launch_bounds__(256, 8) void k_conv(const float* __restrict__ x,
                                                 const float* __restrict__ ws,
                                                 float* __restrict__ ini) {
    __shared__ float sx[3][28][36];
    const int bx = blockIdx.x, by = blockIdx.y, b = blockIdx.z;
    const int t = threadIdx.x;
    const float* Kw   = ws + WS_K;
    const float* Beta = ws + WS_BETA;
    const float* W9   = ws + WS_W9;
    const float* Bt   = ws + WS_BT;
    const int gh0 = by * 20, gw0 = bx * 20;
    bool edgeblk = (by == 0) | (by == 15) | (bx == 0) | (bx == 15);

    if (!edgeblk) {
        for (int i = t; i < 588; i += 256) {         // 3*28*7 float4 rows
            int ci = i / 196; int rem = i - ci * 196;
            int rr = rem / 7, c4 = rem - rr * 7;
            float4 v = *(const float4*)&x[(b * 3 + ci) * 102400 +
                                          (gh0 - 4 + rr) * 320 + (gw0 - 4) + c4 * 4];
            *(float4*)&sx[ci][rr][c4 * 4] = v;
        }
    } else {
        for (int idx = t; idx < 3 * 28 * 28; idx += 256) {
            int ci = idx / 784; int rem = idx - ci * 784;
            int rr = rem / 28, cc = rem - rr * 28;
            int gh = gh0 - 4 + rr, gw = gw0 - 4 + cc;
            float v = 0.f;
            if ((unsigned)gh < 320u && (unsigned)gw < 320u)
                v = x[(b * 3 + ci) * 102400 + gh * 320 + gw];
            sx[ci][rr][cc] = v;
        }
    }
    __syncthreads();

    const int lh = t / 10, lw0 = (t % 10) * 2;   // valid for t<200
    if (t < 200) {
        float acc0[2], acc1[2];
        float bt0 = Bt[0], bt1 = Bt[1];
        acc0[0] = bt0; acc0[1] = bt0; acc1[0] = bt1; acc1[1] = bt1;
        #pragma unroll
        for (int ci = 0; ci < 3; ++ci) {
            #pragma unroll
            for (int dy = 0; dy < 9; ++dy) {
                const float* xr = &sx[ci][lh + dy][lw0];
                float2 y0 = *(const float2*)(xr);
                float2 y1 = *(const float2*)(xr + 2);
                float2 y2 = *(const float2*)(xr + 4);
                float2 y3 = *(const float2*)(xr + 6);
                float2 y4 = *(const float2*)(xr + 8);
                float xv[10] = {y0.x, y0.y, y1.x, y1.y, y2.x,
                                y2.y, y3.x, y3.y, y4.x, y4.y};
                #pragma unroll
                for (int dx = 0; dx < 9; ++dx) {
                    float w0t = W9[ci * 81 + dy * 9 + dx];
                    float w1t = W9[243 + ci * 81 + dy * 9 + dx];
                    acc0[0] += w0t * xv[dx];
                    acc0[1] += w0t * xv[dx + 1];
                    acc1[0] += w1t * xv[dx];
                    acc1[1] += w1t * xv[dx + 1];
                }
            }
        }
        if (edgeblk) {   // exact ring fix: subtract invalid-(a,b) contributions
            #pragma unroll
            for (int j = 0; j < 2; ++j) {
                int h = gh0 + lh, w = gw0 + lw0 + j;
                if (h == 0 || h == 319 || w == 0 || w == 319) {
                    float c0 = 0.f, c1 = 0.f;
                    for (int a = 0; a < 3; ++a) {
                        int hh = h + a - 1;
                        for (int bb = 0; bb < 3; ++bb) {
                            int wwp = w + bb - 1;
                            bool invalid = ((unsigned)hh >= 320u) |
                                           ((unsigned)wwp >= 320u);
                            if (invalid) {
                                c0 += Beta[a * 3 + bb];
                                c1 += Beta[9 + a * 3 + bb];
                                for (int ci = 0; ci < 3; ++ci) {
                                    const float* Kc = Kw + ((a * 3 + bb) * 3 + ci) * 49;
                                    #pragma unroll
                                    for (int u = 0; u < 7; ++u) {
                                        #pragma unroll
                                        for (int v = 0; v < 7; ++v) {
                                            float xv = sx[ci][lh + a + u][lw0 + j + bb + v];
                                            c0 += Kc[u * 7 + v] * xv;
                                            c1 += Kc[1323 + u * 7 + v] * xv;
                                        }
                                    }
                                }
                            }
                        }
                    }
                    acc0[j] -= c0;
                    acc1[j] -= c1;
                }
            }
        }
        size_t obase = (size_t)(b * 2) * 102400 + (gh0 + lh) * 320 + gw0 + lw0;
        *(float2*)&ini[obase] = make_float2(acc0[0], acc0[1]);
        *(float2*)&ini[obase + 102400] = make_float2(acc1[0], acc1[1]);
    }
}

// ---------------------------------------------------------------------------
// Trans. grid (16,16,4), z=(mode<<1)|pg. 1024 blocks; LDS 35.4 KB -> 4/CU
// (exactly resident). No sM: Mt read directly from L2 (coalesced float2).
// OUTPUT RE-LAYOUT: pg-half h goes to k=[64h, 64h+50) with zeros to 64h+64.
// The att dot over k=128 is term-identical (zeros contribute 0), and each
// block writes a CONTIGUOUS 128B half-row per l -> uint4 coalesced stores.
__global__ __launch_bounds__(256) void k_trans(const float* __restrict__ ini,
                                               const float* __restrict__ x,
                                               const float* __restrict__ wfm,
                                               const float* __restrict__ bfm,
                                               const float* __restrict__ ws,
                                               ushort* __restrict__ uiL,
                                               ushort* __restrict__ ufL) {
    __shared__ float  sP[100][68];     // 27.2 KB: patch rows x 64 l (+4 pad)
    __shared__ ushort sOut[64][64];    //  8 KB: l x half-row (50 data + 14 zero)
    int bc = blockIdx.x;   // 0..15
    int lg = blockIdx.y;   // 0..15 strip of 64 patches (20 image rows)
    int zz = blockIdx.z;
    int mode = zz >> 1, pg = zz & 1;
    ushort* outL = mode ? ufL : uiL;
    int t = threadIdx.x;
    const float* Mt = ws + WS_M;
    int b = bc >> 1, c = bc & 1;
    int row0 = lg * 20;

    // ---- stage sP via float4 global reads
    if (mode == 0) {
        for (int e = t; e < 1600; e += 256) {
            int irow = e / 80, c4 = (e % 80) * 4;
            float4 v = *(const float4*)&ini[bc * 102400 + (row0 + irow) * 320 + c4];
            float vv[4] = {v.x, v.y, v.z, v.w};
            #pragma unroll
            for (int k = 0; k < 4; ++k) {
                int col = c4 + k;
                sP[(irow % 10) * 10 + col % 10][(irow / 10) * 32 + col / 10] = vv[k];
            }
        }
    } else {
        float wf0 = wfm[c * 3 + 0], wf1 = wfm[c * 3 + 1], wf2 = wfm[c * 3 + 2];
        float bfv = bfm[c];
        for (int e = t; e < 1600; e += 256) {
            int irow = e / 80, c4 = (e % 80) * 4;
            size_t base = (size_t)b * 3 * 102400 + (row0 + irow) * 320 + c4;
            float4 v0 = *(const float4*)&x[base];
            float4 v1 = *(const float4*)&x[base + 102400];
            float4 v2 = *(const float4*)&x[base + 204800];
            float a0[4] = {v0.x, v0.y, v0.z, v0.w};
            float a1[4] = {v1.x, v1.y, v1.z, v1.w};
            float a2[4] = {v2.x, v2.y, v2.z, v2.w};
            #pragma unroll
            for (int k = 0; k < 4; ++k) {
                int col = c4 + k;
                float val = (bfv + a0[k] * wf0 + a1[k] * wf1 + a2[k] * wf2) * 0.25f;
                sP[(irow % 10) * 10 + col % 10][(irow / 10) * 32 + col / 10] = val;
            }
        }
    }
    __syncthreads();

    // ---- trans: thread (py,lx) owns p0=2py(,+1), l = lx*8..+7; 200 threads.
    // Lanes 200..255 zero sOut slots [50,64) (448 uints over 56 lanes x 8).
    if (t < 200) {
        int py = t / 8, lx = t % 8;
        int p0 = py * 2, lo = lx * 8;
        float acc[2][8];
        #pragma unroll
        for (int i = 0; i < 2; ++i)
            #pragma unroll
            for (int j = 0; j < 8; ++j) acc[i][j] = 0.f;
        #pragma unroll 5
        for (int r = 0; r < 100; ++r) {
            float2 mv = *(const float2*)&Mt[r * 100 + pg * 50 + p0];
            f32x4 b0 = *(const f32x4*)&sP[r][lo];
            f32x4 b1 = *(const f32x4*)&sP[r][lo + 4];
            #pragma unroll
            for (int j = 0; j < 4; ++j) {
                acc[0][j]     += mv.x * b0[j];
                acc[0][4 + j] += mv.x * b1[j];
                acc[1][j]     += mv.y * b0[j];
                acc[1][4 + j] += mv.y * b1[j];
            }
        }
        #pragma unroll
        for (int j = 0; j < 8; ++j) {
            unsigned v0 = f2bf(fmaxf(acc[0][j], 0.f));
            unsigned v1 = f2bf(fmaxf(acc[1][j], 0.f));
            *(unsigned*)&sOut[lo + j][p0] = v0 | (v1 << 16);
        }
    } else {
        #pragma unroll
        for (int k = 0; k < 8; ++k) {
            int idx = (t - 200) + 56 * k;   // 0..447
            int l = idx / 7, q = idx % 7;
            *(unsigned*)&sOut[l][50 + q * 2] = 0u;
        }
    }
    __syncthreads();

    // ---- coalesced writeout: 256 thr = 64 l x 4 lanes; 2x uint4 per thread
    {
        int l = t >> 2, q = t & 3;
        size_t rowb = ((size_t)bc * 1024 + lg * 64 + l) * 128 + pg * 64;
        *(uint4*)&outL[rowb + q * 8]      = *(const uint4*)&sOut[l][q * 8];
        *(uint4*)&outL[rowb + 32 + q * 8] = *(const uint4*)&sOut[l][32 + q * 8];
    }
}

// ---------------------------------------------------------------------------
// att[bc][l][m] = (1/100) * sum_p ui[l][p]*uf[m][p], bf16 MFMA 16x16x32.
// 64x128 tile/block, grid (8,16,16) = 2048 blocks. 4 waves 2x2.
__global__ __launch_bounds__(256) void k_att(const ushort* __restrict__ ui,
                                             const ushort* __restrict__ uf,
                                             float* __restrict__ out) {
    int bc   = blockIdx.z;
    int row0 = blockIdx.y * 64, col0 = blockIdx.x * 128;
    int wave = threadIdx.x >> 6, lane = threadIdx.x & 63;
    int r0 = row0 + (wave >> 1) * 32;
    int c0 = col0 + (wave & 1) * 64;
    int m = lane & 15, quad = lane >> 4;
    const ushort* ub = ui + (size_t)bc * 1024 * 128;
    const ushort* vb = uf + (size_t)bc * 1024 * 128;
    f32x4 acc[2][4];
    #pragma unroll
    for (int i = 0; i < 2; ++i)
        #pragma unroll
        for (int j = 0; j < 4; ++j)
            acc[i][j] = (f32x4){0.f, 0.f, 0.f, 0.f};
    #pragma unroll
    for (int k0 = 0; k0 < 128; k0 += 32) {
        bf16x8 af[2], bfr[4];
        #pragma unroll
        for (int i = 0; i < 2; ++i)
            af[i] = *(const bf16x8*)&ub[(size_t)(r0 + i * 16 + m) * 128 + k0 + quad * 8];
        #pragma unroll
        for (int j = 0; j < 4; ++j)
            bfr[j] = *(const bf16x8*)&vb[(size_t)(c0 + j * 16 + m) * 128 + k0 + quad * 8];
        #pragma unroll
        for (int i = 0; i < 2; ++i)
            #pragma unroll
            for (int j = 0; j < 4; ++j)
                acc[i][j] = __builtin_amdgcn_mfma_f32_16x16x32_bf16(af[i], bfr[j], acc[i][j], 0, 0, 0);
    }
    // C/D: col = lane&15, row = quad*4 + reg (m89/m91-verified)
    #pragma unroll
    for (int i = 0; i < 2; ++i) {
        #pragma unroll
        for (int r = 0; r < 4; ++r) {
            int row = r0 + i * 16 + quad * 4 + r;
            float* o = out + ((size_t)bc * 1024 + row) * 1024;
            #pragma unroll
            for (int j = 0; j < 4; ++j)
                o[c0 + j * 16 + m] = acc[i][j][r] * 0.01f;
        }
    }
}

extern "C" void kernel_launch(void* const* d_in, const int* in_sizes, int n_in,
                              void* d_out, int out_size, void* d_ws, size_t ws_size,
                              hipStream_t stream) {
    const float* x       = (const float*)d_in[0];
    const float* w_conv1 = (const float*)d_in[1];
    const float* b_conv1 = (const float*)d_in[2];
    const float* w_conv2 = (const float*)d_in[3];
    const float* b_conv2 = (const float*)d_in[4];
    const float* w_fm    = (const float*)d_in[5];
    const float* b_fm    = (const float*)d_in[6];
    const float* w_lin1  = (const float*)d_in[7];
    const float* w_lin2  = (const float*)d_in[8];
    float* out = (float*)d_out;
    float* ws  = (float*)d_ws;
    ushort* uiL = (ushort*)(ws + WS_UIT);
    ushort* ufL = (ushort*)(ws + WS_UFT);

    k_prep<<<45, 256, 0, stream>>>(w_lin1, w_lin2, w_conv1, b_conv1, w_conv2, b_conv2, ws);
    k_conv<<<dim3(16, 16, 8), 256, 0, stream>>>(x, ws, ws + WS_INI);
    k_trans<<<dim3(16, 16, 4), 256, 0, stream>>>(ws + WS_INI, x, w_fm, b_fm, ws, uiL, ufL);
    k_att<<<dim3(8, 16, 16), 256, 0, stream>>>(uiL, ufL, out);
}

// Round 10
// 196.694 us; speedup vs baseline: 1.0592x; 1.0592x over previous
//
#include <hip/hip_runtime.h>

// Workspace layout (float offsets)
#define WS_M      0        // Mt[r*100+p] = M[p][r] where M = w_lin2 @ w_lin1, 10000 floats
#define WS_K      10000    // K[c][a][b][ci][u][v], 2646 floats
#define WS_BETA   12646    // beta[c][a][b], 18 floats
#define WS_W9     12664    // W9[c][ci][dy][dx], 486 floats
#define WS_BT     13150    // beta_tot[c] (interior combined bias), 2 floats
#define WS_INI    16384    // ini[b][c][h][w] f32, 1,638,400 floats
#define WS_UIT    (16384 + 1638400)      // uiL[bc][l][128] bf16 (halves at k=0,64)
#define WS_UFT    (16384 + 2*1638400)    // ufL[bc][l][128] bf16

typedef short bf16x8 __attribute__((ext_vector_type(8)));
typedef float f32x4  __attribute__((ext_vector_type(4)));

__device__ inline ushort f2bf(float f) {   // round-to-nearest-even
    unsigned u = __float_as_uint(f);
    unsigned r = (u + 0x7fffu + ((u >> 16) & 1u)) >> 16;
    return (ushort)r;
}

// ---------------------------------------------------------------------------
// Prep. blocks 0..39: Mt. blocks 40..42: K (block 40 also Beta+Bt).
// blocks 43..44: W9 from raw weights.
__global__ __launch_bounds__(256) void k_prep(const float* __restrict__ wl1,
                                              const float* __restrict__ wl2,
                                              const float* __restrict__ wc1,
                                              const float* __restrict__ bc1,
                                              const float* __restrict__ wc2,
                                              const float* __restrict__ bc2,
                                              float* __restrict__ ws) {
    int blk = blockIdx.x;
    int t = threadIdx.x;
    if (blk < 40) {
        int idx = blk * 256 + t;
        if (idx < 10000) {
            int p = idx / 100, r = idx % 100;
            float s = 0.f;
            for (int q = 0; q < 200; ++q)
                s += wl2[p * 200 + q] * wl1[q * 100 + r];
            ws[WS_M + r * 100 + p] = s;
        }
        return;
    }
    __shared__ float swc1[9408];   // 64*3*49
    __shared__ float swc2[1152];   // 2*64*9
    __shared__ float sBeta[18];
    for (int i = t; i < 9408; i += 256) swc1[i] = wc1[i];
    for (int i = t; i < 1152; i += 256) swc2[i] = wc2[i];
    __syncthreads();
    if (blk < 43) {
        int base = (blk - 40) * 882;
        for (int ii = t; ii < 882; ii += 256) {
            int idx = base + ii;
            int v = idx % 7; int t1 = idx / 7;
            int u = t1 % 7;  int t2 = t1 / 7;
            int ci = t2 % 3; int t3 = t2 / 3;
            int b = t3 % 3;  int t4 = t3 / 3;
            int a = t4 % 3;  int c = t4 / 3;
            float s = 0.f;
            for (int c64 = 0; c64 < 64; ++c64)
                s += swc2[((c * 64 + c64) * 3 + a) * 3 + b] *
                     swc1[((c64 * 3 + ci) * 7 + u) * 7 + v];
            ws[WS_K + idx] = s;
        }
        if (blk == 40) {
            if (t < 18) {
                int b = t % 3; int a = (t / 3) % 3; int c = t / 9;
                float s = 0.f;
                for (int c64 = 0; c64 < 64; ++c64)
                    s += swc2[((c * 64 + c64) * 3 + a) * 3 + b] * bc1[c64];
                sBeta[t] = s; ws[WS_BETA + t] = s;
            }
            __syncthreads();
            if (t < 2) {
                float s = bc2[t];
                for (int j2 = 0; j2 < 9; ++j2) s += sBeta[t * 9 + j2];
                ws[WS_BT + t] = s;
            }
        }
    } else {
        int idx = (blk - 43) * 243 + t;
        if (t < 243) {
            int dx = idx % 9; int t1 = idx / 9;
            int dy = t1 % 9;  int t2 = t1 / 9;
            int ci = t2 % 3;  int c = t2 / 3;
            float s = 0.f;
            for (int a = 0; a < 3; ++a) {
                int u = dy - a; if (u < 0 || u > 6) continue;
                for (int b = 0; b < 3; ++b) {
                    int v = dx - b; if (v < 0 || v > 6) continue;
                    for (int c64 = 0; c64 < 64; ++c64)
                        s += swc2[((c * 64 + c64) * 3 + a) * 3 + b] *
                             swc1[((c64 * 3 + ci) * 7 + u) * 7 + v];
                }
            }
            ws[WS_W9 + idx] = s;   // layout c*243 + ci*81 + dy*9 + dx
        }
    }
}

// ---------------------------------------------------------------------------
// Conv, 32x32 tile, 4 px/thread (ALL 256 threads), weights in LDS (broadcast
// reads), inline exact ring-correction on edge blocks. Grid (10,10,8) = 800
// blocks, LDS 21.2 KB. sx stride 40: float4 reads cover all 32 banks/row ->
// conflict-free b128; 3 LDS floats/output (vs 5 in the 20x20 version).
__global__ __launch_bounds__(256, 4) void k_conv(const float* __restrict__ x,
                                                 const float* __restrict__ ws,
                                                 float* __restrict__ ini) {
    __shared__ float sx[3][40][40];
    __shared__ float sW9[488];          // 486 W9 + Bt[2]
    const int bx = blockIdx.x, by = blockIdx.y, b = blockIdx.z;
    const int t = threadIdx.x;
    const int gh0 = by * 32, gw0 = bx * 32;
    bool edgeblk = (by == 0) | (by == 9) | (bx == 0) | (bx == 9);

    for (int i = t; i < 486; i += 256) sW9[i] = ws[WS_W9 + i];
    if (t < 2) sW9[486 + t] = ws[WS_BT + t];

    if (!edgeblk) {
        for (int i = t; i < 1200; i += 256) {        // 3 ci x 40 rows x 10 f4
            int ci = i / 400; int rem = i - ci * 400;
            int rr = rem / 10, c4 = rem - rr * 10;
            float4 v = *(const float4*)&x[(b * 3 + ci) * 102400 +
                                          (gh0 - 4 + rr) * 320 + (gw0 - 4) + c4 * 4];
            *(float4*)&sx[ci][rr][c4 * 4] = v;
        }
    } else {
        for (int idx = t; idx < 4800; idx += 256) {
            int ci = idx / 1600; int rem = idx - ci * 1600;
            int rr = rem / 40, cc = rem - rr * 40;
            int gh = gh0 - 4 + rr, gw = gw0 - 4 + cc;
            float v = 0.f;
            if ((unsigned)gh < 320u && (unsigned)gw < 320u)
                v = x[(b * 3 + ci) * 102400 + gh * 320 + gw];
            sx[ci][rr][cc] = v;
        }
    }
    __syncthreads();

    const int r = t >> 3, cg = t & 7;
    const int h = gh0 + r, w0c = gw0 + cg * 4;
    float acc0[4], acc1[4];
    float bt0 = sW9[486], bt1 = sW9[487];
    #pragma unroll
    for (int j = 0; j < 4; ++j) { acc0[j] = bt0; acc1[j] = bt1; }
    #pragma unroll
    for (int ci = 0; ci < 3; ++ci) {
        #pragma unroll
        for (int dy = 0; dy < 9; ++dy) {
            const float* xr = &sx[ci][r + dy][cg * 4];
            float4 xa = *(const float4*)(xr);
            float4 xb = *(const float4*)(xr + 4);
            float4 xc = *(const float4*)(xr + 8);
            float xv[12] = {xa.x, xa.y, xa.z, xa.w,
                            xb.x, xb.y, xb.z, xb.w,
                            xc.x, xc.y, xc.z, xc.w};
            const float* w0r = &sW9[ci * 81 + dy * 9];
            const float* w1r = &sW9[243 + ci * 81 + dy * 9];
            #pragma unroll
            for (int dx = 0; dx < 9; ++dx) {
                float w0t = w0r[dx];
                float w1t = w1r[dx];
                #pragma unroll
                for (int j = 0; j < 4; ++j) {
                    acc0[j] += w0t * xv[dx + j];
                    acc1[j] += w1t * xv[dx + j];
                }
            }
        }
    }
    if (edgeblk) {   // exact ring fix: subtract invalid-(a,b) contributions
        const float* Kw   = ws + WS_K;
        const float* Beta = ws + WS_BETA;
        #pragma unroll
        for (int j = 0; j < 4; ++j) {
            int w = w0c + j;
            if (h == 0 || h == 319 || w == 0 || w == 319) {
                float c0 = 0.f, c1 = 0.f;
                for (int a = 0; a < 3; ++a) {
                    int hh = h + a - 1;
                    for (int bb = 0; bb < 3; ++bb) {
                        int wwp = w + bb - 1;
                        bool invalid = ((unsigned)hh >= 320u) |
                                       ((unsigned)wwp >= 320u);
                        if (invalid) {
                            c0 += Beta[a * 3 + bb];
                            c1 += Beta[9 + a * 3 + bb];
                            for (int ci = 0; ci < 3; ++ci) {
                                const float* Kc = Kw + ((a * 3 + bb) * 3 + ci) * 49;
                                #pragma unroll
                                for (int u = 0; u < 7; ++u) {
                                    #pragma unroll
                                    for (int v = 0; v < 7; ++v) {
                                        float xv = sx[ci][r + a + u][cg * 4 + j + bb + v];
                                        c0 += Kc[u * 7 + v] * xv;
                                        c1 += Kc[1323 + u * 7 + v] * xv;
                                    }
                                }
                            }
                        }
                    }
                }
                acc0[j] -= c0;
                acc1[j] -= c1;
            }
        }
    }
    size_t obase = (size_t)(b * 2) * 102400 + h * 320 + w0c;
    *(float4*)&ini[obase] = make_float4(acc0[0], acc0[1], acc0[2], acc0[3]);
    *(float4*)&ini[obase + 102400] = make_float4(acc1[0], acc1[1], acc1[2], acc1[3]);
}

// ---------------------------------------------------------------------------
// Trans. grid (16,16,4), z=(mode<<1)|pg. 1024 blocks; LDS 35.4 KB -> 4/CU.
// No sM: Mt read directly from L2 (coalesced float2).
// OUTPUT RE-LAYOUT: pg-half h goes to k=[64h, 64h+50) with zeros to 64h+64.
// att dot over k=128 is term-identical (zeros contribute 0); each block
// writes a CONTIGUOUS 128B half-row per l -> uint4 coalesced stores.
__global__ __launch_bounds__(256) void k_trans(const float* __restrict__ ini,
                                               const float* __restrict__ x,
                                               const float* __restrict__ wfm,
                                               const float* __restrict__ bfm,
                                               const float* __restrict__ ws,
                                               ushort* __restrict__ uiL,
                                               ushort* __restrict__ ufL) {
    __shared__ float  sP[100][68];     // 27.2 KB: patch rows x 64 l (+4 pad)
    __shared__ ushort sOut[64][64];    //  8 KB: l x half-row (50 data + 14 zero)
    int bc = blockIdx.x;   // 0..15
    int lg = blockIdx.y;   // 0..15 strip of 64 patches (20 image rows)
    int zz = blockIdx.z;
    int mode = zz >> 1, pg = zz & 1;
    ushort* outL = mode ? ufL : uiL;
    int t = threadIdx.x;
    const float* Mt = ws + WS_M;
    int b = bc >> 1, c = bc & 1;
    int row0 = lg * 20;

    // ---- stage sP via float4 global reads
    if (mode == 0) {
        for (int e = t; e < 1600; e += 256) {
            int irow = e / 80, c4 = (e % 80) * 4;
            float4 v = *(const float4*)&ini[bc * 102400 + (row0 + irow) * 320 + c4];
            float vv[4] = {v.x, v.y, v.z, v.w};
            #pragma unroll
            for (int k = 0; k < 4; ++k) {
                int col = c4 + k;
                sP[(irow % 10) * 10 + col % 10][(irow / 10) * 32 + col / 10] = vv[k];
            }
        }
    } else {
        float wf0 = wfm[c * 3 + 0], wf1 = wfm[c * 3 + 1], wf2 = wfm[c * 3 + 2];
        float bfv = bfm[c];
        for (int e = t; e < 1600; e += 256) {
            int irow = e / 80, c4 = (e % 80) * 4;
            size_t base = (size_t)b * 3 * 102400 + (row0 + irow) * 320 + c4;
            float4 v0 = *(const float4*)&x[base];
            float4 v1 = *(const float4*)&x[base + 102400];
            float4 v2 = *(const float4*)&x[base + 204800];
            float a0[4] = {v0.x, v0.y, v0.z, v0.w};
            float a1[4] = {v1.x, v1.y, v1.z, v1.w};
            float a2[4] = {v2.x, v2.y, v2.z, v2.w};
            #pragma unroll
            for (int k = 0; k < 4; ++k) {
                int col = c4 + k;
                float val = (bfv + a0[k] * wf0 + a1[k] * wf1 + a2[k] * wf2) * 0.25f;
                sP[(irow % 10) * 10 + col % 10][(irow / 10) * 32 + col / 10] = val;
            }
        }
    }
    __syncthreads();

    // ---- trans: thread (py,lx) owns p0=2py(,+1), l = lx*8..+7; 200 threads.
    // Lanes 200..255 zero sOut slots [50,64) (448 uints over 56 lanes x 8).
    if (t < 200) {
        int py = t / 8, lx = t % 8;
        int p0 = py * 2, lo = lx * 8;
        float acc[2][8];
        #pragma unroll
        for (int i = 0; i < 2; ++i)
            #pragma unroll
            for (int j = 0; j < 8; ++j) acc[i][j] = 0.f;
        #pragma unroll 5
        for (int r = 0; r < 100; ++r) {
            float2 mv = *(const float2*)&Mt[r * 100 + pg * 50 + p0];
            f32x4 b0 = *(const f32x4*)&sP[r][lo];
            f32x4 b1 = *(const f32x4*)&sP[r][lo + 4];
            #pragma unroll
            for (int j = 0; j < 4; ++j) {
                acc[0][j]     += mv.x * b0[j];
                acc[0][4 + j] += mv.x * b1[j];
                acc[1][j]     += mv.y * b0[j];
                acc[1][4 + j] += mv.y * b1[j];
            }
        }
        #pragma unroll
        for (int j = 0; j < 8; ++j) {
            unsigned v0 = f2bf(fmaxf(acc[0][j], 0.f));
            unsigned v1 = f2bf(fmaxf(acc[1][j], 0.f));
            *(unsigned*)&sOut[lo + j][p0] = v0 | (v1 << 16);
        }
    } else {
        #pragma unroll
        for (int k = 0; k < 8; ++k) {
            int idx = (t - 200) + 56 * k;   // 0..447
            int l = idx / 7, q = idx % 7;
            *(unsigned*)&sOut[l][50 + q * 2] = 0u;
        }
    }
    __syncthreads();

    // ---- coalesced writeout: 256 thr = 64 l x 4 lanes; 2x uint4 per thread
    {
        int l = t >> 2, q = t & 3;
        size_t rowb = ((size_t)bc * 1024 + lg * 64 + l) * 128 + pg * 64;
        *(uint4*)&outL[rowb + q * 8]      = *(const uint4*)&sOut[l][q * 8];
        *(uint4*)&outL[rowb + 32 + q * 8] = *(const uint4*)&sOut[l][32 + q * 8];
    }
}

// ---------------------------------------------------------------------------
// att[bc][l][m] = (1/100) * sum_p ui[l][p]*uf[m][p], bf16 MFMA 16x16x32.
// 64x128 tile/block, grid (8,16,16) = 2048 blocks. 4 waves 2x2.
__global__ __launch_bounds__(256) void k_att(const ushort* __restrict__ ui,
                                             const ushort* __restrict__ uf,
                                             float* __restrict__ out) {
    int bc   = blockIdx.z;
    int row0 = blockIdx.y * 64, col0 = blockIdx.x * 128;
    int wave = threadIdx.x >> 6, lane = threadIdx.x & 63;
    int r0 = row0 + (wave >> 1) * 32;
    int c0 = col0 + (wave & 1) * 64;
    int m = lane & 15, quad = lane >> 4;
    const ushort* ub = ui + (size_t)bc * 1024 * 128;
    const ushort* vb = uf + (size_t)bc * 1024 * 128;
    f32x4 acc[2][4];
    #pragma unroll
    for (int i = 0; i < 2; ++i)
        #pragma unroll
        for (int j = 0; j < 4; ++j)
            acc[i][j] = (f32x4){0.f, 0.f, 0.f, 0.f};
    #pragma unroll
    for (int k0 = 0; k0 < 128; k0 += 32) {
        bf16x8 af[2], bfr[4];
        #pragma unroll
        for (int i = 0; i < 2; ++i)
            af[i] = *(const bf16x8*)&ub[(size_t)(r0 + i * 16 + m) * 128 + k0 + quad * 8];
        #pragma unroll
        for (int j = 0; j < 4; ++j)
            bfr[j] = *(const bf16x8*)&vb[(size_t)(c0 + j * 16 + m) * 128 + k0 + quad * 8];
        #pragma unroll
        for (int i = 0; i < 2; ++i)
            #pragma unroll
            for (int j = 0; j < 4; ++j)
                acc[i][j] = __builtin_amdgcn_mfma_f32_16x16x32_bf16(af[i], bfr[j], acc[i][j], 0, 0, 0);
    }
    // C/D: col = lane&15, row = quad*4 + reg (m89/m91-verified)
    #pragma unroll
    for (int i = 0; i < 2; ++i) {
        #pragma unroll
        for (int r = 0; r < 4; ++r) {
            int row = r0 + i * 16 + quad * 4 + r;
            float* o = out + ((size_t)bc * 1024 + row) * 1024;
            #pragma unroll
            for (int j = 0; j < 4; ++j)
                o[c0 + j * 16 + m] = acc[i][j][r] * 0.01f;
        }
    }
}

extern "C" void kernel_launch(void* const* d_in, const int* in_sizes, int n_in,
                              void* d_out, int out_size, void* d_ws, size_t ws_size,
                              hipStream_t stream) {
    const float* x       = (const float*)d_in[0];
    const float* w_conv1 = (const float*)d_in[1];
    const float* b_conv1 = (const float*)d_in[2];
    const float* w_conv2 = (const float*)d_in[3];
    const float* b_conv2 = (const float*)d_in[4];
    const float* w_fm    = (const float*)d_in[5];
    const float* b_fm    = (const float*)d_in[6];
    const float* w_lin1  = (const float*)d_in[7];
    const float* w_lin2  = (const float*)d_in[8];
    float* out = (float*)d_out;
    float* ws  = (float*)d_ws;
    ushort* uiL = (ushort*)(ws + WS_UIT);
    ushort* ufL = (ushort*)(ws + WS_UFT);

    k_prep<<<45, 256, 0, stream>>>(w_lin1, w_lin2, w_conv1, b_conv1, w_conv2, b_conv2, ws);
    k_conv<<<dim3(10, 10, 8), 256, 0, stream>>>(x, ws, ws + WS_INI);
    k_trans<<<dim3(16, 16, 4), 256, 0, stream>>>(ws + WS_INI, x, w_fm, b_fm, ws, uiL, ufL);
    k_att<<<dim3(8, 16, 16), 256, 0, stream>>>(uiL, ufL, out);
}